// Round 13
// baseline (133.502 us; speedup 1.0000x reference)
//
#include <hip/hip_runtime.h>
#include <cstdint>
#include <cstddef>

typedef unsigned short u16;
typedef unsigned int u32;
typedef __bf16 bf16x8 __attribute__((ext_vector_type(8)));
typedef float f32x4 __attribute__((ext_vector_type(4)));
typedef u32 u32x4 __attribute__((ext_vector_type(4)));
typedef u32 u32x2 __attribute__((ext_vector_type(2)));
typedef unsigned short u16x8 __attribute__((ext_vector_type(8)));
typedef short s16x4 __attribute__((ext_vector_type(4)));

#if __has_builtin(__builtin_amdgcn_mfma_f32_16x16x16bf16_1k)
#define HAVE_MFMA16 1
#else
#define HAVE_MFMA16 0
#endif

// f32 -> bf16 round-to-nearest-even (finite inputs only)
__device__ __forceinline__ u16 f2bf(float f) {
    u32 u = __float_as_uint(f);
    u += 0x7fffu + ((u >> 16) & 1u);
    return (u16)(u >> 16);
}

// raw exp2: single v_exp_f32 (no OCML lib-call guard code; denormals flush
// to 0, which is exactly right for softmax tail underflow)
__device__ __forceinline__ float fexp2(float x) {
    float r;
    asm("v_exp_f32 %0, %1" : "=v"(r) : "v"(x));
    return r;
}

// async global->LDS, 16B per lane. LDS ptr must be wave-uniform; HW adds lane*16.
__device__ __forceinline__ void gl16(const void* g, void* l) {
    __builtin_amdgcn_global_load_lds(
        (const __attribute__((address_space(1))) unsigned int*)g,
        (__attribute__((address_space(3))) unsigned int*)l, 16, 0, 0);
}

// ---------------------------------------------------------------- conversions
__global__ __launch_bounds__(256) void cvt_x_k(const float* __restrict__ x,
                                               u16* __restrict__ o) {
    int i = blockIdx.x * 256 + threadIdx.x;
    const float4* xv = (const float4*)x;
    float4 a = xv[2 * i], b = xv[2 * i + 1];
    ushort4 r0, r1;
    r0.x = f2bf(a.x); r0.y = f2bf(a.y); r0.z = f2bf(a.z); r0.w = f2bf(a.w);
    r1.x = f2bf(b.x); r1.y = f2bf(b.y); r1.z = f2bf(b.z); r1.w = f2bf(b.w);
    ((ushort4*)o)[2 * i] = r0;
    ((ushort4*)o)[2 * i + 1] = r1;
}

// All four W [1024][1024] f32 (k,n) -> bf16 (n,k) transposes in ONE launch.
// blockIdx.z selects {Wq,Wk,Wv,Wo}.
__global__ __launch_bounds__(256) void cvt_wT4_k(const float* __restrict__ Wq,
                                                 const float* __restrict__ Wk,
                                                 const float* __restrict__ Wv,
                                                 const float* __restrict__ Wo,
                                                 u16* __restrict__ oqkv,
                                                 u16* __restrict__ oo) {
    __shared__ float tile[64][65];
    const int z = blockIdx.z;
    const float* W = (z == 0) ? Wq : (z == 1) ? Wk : (z == 2) ? Wv : Wo;
    u16* o = (z < 3) ? (oqkv + ((size_t)z << 20)) : oo;
    const int bx = blockIdx.x, by = blockIdx.y;
    const int t = threadIdx.x, tn = t & 63, tr = t >> 6;
#pragma unroll
    for (int r = 0; r < 16; ++r) {
        int kk = r * 4 + tr;
        tile[kk][tn] = W[(size_t)(by * 64 + kk) * 1024 + bx * 64 + tn];
    }
    __syncthreads();
#pragma unroll
    for (int r = 0; r < 16; ++r) {
        int nn = r * 4 + tr;
        o[(size_t)(bx * 64 + nn) * 1024 + by * 64 + tn] = f2bf(tile[tn][nn]);
    }
}

// ------------------------------------------------------- QKV GEMM 128x256
// A [4096][1024] bf16, Bt [3072][1024] bf16. 512 threads = 8 waves (2x4).
// 3-buffer depth-2 counted-vmcnt pipeline; 3 gl16/wave/iter -> vmcnt(3).
// Zero-conflict LDS swizzle (both-sides, rule #21). 72KB LDS -> 2 blocks/CU
// = 16 waves/CU = 4 waves/SIMD (2x the TLP of the 128^2 version).
// Epilogue -> q (pre-scaled by 0.125*log2e), k: [BH][2048][64],
// v transposed: [BH][64][2048].
__global__ __launch_bounds__(512, 4) void gemm256_k(
    const u16* __restrict__ A, const u16* __restrict__ Bt,
    const float* __restrict__ bias0, const float* __restrict__ bias1,
    const float* __restrict__ bias2,
    u16* __restrict__ oq, u16* __restrict__ ok_, u16* __restrict__ ov) {
    __shared__ __align__(16) u16 As[3 * 128 * 32];   // 24KB
    __shared__ __align__(16) u16 Bs[3 * 256 * 32];   // 48KB
    const int t = threadIdx.x, w = t >> 6, lane = t & 63;
    const int lr = lane & 15, lg = lane >> 4;
    const int brow = blockIdx.x * 128, bcol = blockIdx.y * 256;
    const int wr = w >> 2, wc = w & 3;
    const char* Ab = (const char*)A + (size_t)brow * 2048;
    const char* Bb = (const char*)Bt + (size_t)bcol * 2048;
    const int lrow = lane >> 2;
    // swizzled source column: LDS[row][c] holds G[row][c ^ ((row>>1)&3)]
    const int lcol = (((lane & 3) ^ ((lane >> 3) & 3)) << 4);
    // staging: wave w covers A rows [w*16, w*16+16) (1 gl16) and
    // B rows [w*32, w*32+32) (2 gl16). 16 rows x 64B = 1KB per gl16.
    const size_t gaA = (size_t)(w * 16 + lrow) * 2048 + lcol;
    const size_t gaB0 = (size_t)(w * 32 + lrow) * 2048 + lcol;
    const size_t gaB1 = (size_t)(w * 32 + 16 + lrow) * 2048 + lcol;
    const int dA = w * 1024, dB0 = w * 2048, dB1 = w * 2048 + 1024;
    // swizzled read column offset
    const int rsw = ((lg ^ ((lr >> 1) & 3)) << 4);

    f32x4 acc[4][4];
#pragma unroll
    for (int m = 0; m < 4; ++m)
#pragma unroll
        for (int n = 0; n < 4; ++n) acc[m][n] = (f32x4){0.f, 0.f, 0.f, 0.f};

    // prologue: stage K-steps 0 and 1 into buffers 0,1 (issue order matters)
    gl16(Ab + gaA, (char*)As + dA);
    gl16(Bb + gaB0, (char*)Bs + dB0);
    gl16(Bb + gaB1, (char*)Bs + dB1);
    gl16(Ab + gaA + 64, (char*)As + 8192 + dA);
    gl16(Bb + gaB0 + 64, (char*)Bs + 16384 + dB0);
    gl16(Bb + gaB1 + 64, (char*)Bs + 16384 + dB1);

    for (int tt = 0; tt < 32; ++tt) {
        if (tt < 31) {
            asm volatile("s_waitcnt vmcnt(3)" ::: "memory");
        } else {
            asm volatile("s_waitcnt vmcnt(0)" ::: "memory");
        }
        __builtin_amdgcn_s_barrier();
        __builtin_amdgcn_sched_barrier(0);
        if (tt < 30) {   // stage K-step t+2 into buffer (t+2)%3
            const int nb = (tt + 2) % 3;
            const size_t ko = (size_t)(tt + 2) * 64;   // 32 elems * 2B
            gl16(Ab + gaA + ko, (char*)As + nb * 8192 + dA);
            gl16(Bb + gaB0 + ko, (char*)Bs + nb * 16384 + dB0);
            gl16(Bb + gaB1 + ko, (char*)Bs + nb * 16384 + dB1);
        }
        const char* AsB = (const char*)As + (tt % 3) * 8192;
        const char* BsB = (const char*)Bs + (tt % 3) * 16384;
        bf16x8 af[4], bfr[4];
#pragma unroll
        for (int m = 0; m < 4; ++m)
            af[m] = *(const bf16x8*)(AsB + (wr * 64 + m * 16 + lr) * 64 + rsw);
#pragma unroll
        for (int n = 0; n < 4; ++n)
            bfr[n] = *(const bf16x8*)(BsB + (wc * 64 + n * 16 + lr) * 64 + rsw);
#pragma unroll
        for (int m = 0; m < 4; ++m)
#pragma unroll
            for (int n = 0; n < 4; ++n)
                acc[m][n] = __builtin_amdgcn_mfma_f32_16x16x32_bf16(af[m], bfr[n],
                                                                    acc[m][n], 0, 0, 0);
    }

    const float QSCALE = 0.125f * 1.44269504f;
#pragma unroll
    for (int n = 0; n < 4; ++n) {
        const int col = bcol + wc * 64 + n * 16 + lr;
#pragma unroll
        for (int m = 0; m < 4; ++m)
#pragma unroll
            for (int r = 0; r < 4; ++r) {
                int row = brow + wr * 64 + m * 16 + 4 * lg + r;
                int b = row >> 11, l = row & 2047;
                float val = acc[m][n][r];
                if (col < 1024) {
                    int hh = col >> 6, d = col & 63;
                    oq[(((size_t)b * 16 + hh) * 2048 + l) * 64 + d] =
                        f2bf((val + bias0[col]) * QSCALE);
                } else if (col < 2048) {
                    int c = col - 1024, hh = c >> 6, d = c & 63;
                    ok_[(((size_t)b * 16 + hh) * 2048 + l) * 64 + d] =
                        f2bf(val + bias1[c]);
                } else {
                    int c = col - 2048, hh = c >> 6, d = c & 63;
                    ov[(((size_t)b * 16 + hh) * 64 + d) * 2048 + l] =
                        f2bf(val + bias2[c]);
                }
            }
    }
}

// ---------------------------------------------------------------- GEMM 128x128
// (out-proj only now: A [4096][1024] x Wo^T + bias -> f32 out.)
// 3-buffer depth-2 counted-vmcnt pipeline; zero-conflict swizzle.
__global__ __launch_bounds__(256) void gemm_k(
    const u16* __restrict__ A, const u16* __restrict__ Bt,
    const float* __restrict__ bias0, float* __restrict__ oc) {
    __shared__ __align__(16) u16 As[3 * 128 * 32];   // 24KB
    __shared__ __align__(16) u16 Bs[3 * 128 * 32];   // 24KB
    const int t = threadIdx.x, w = t >> 6, lane = t & 63;
    const int lr = lane & 15, lg = lane >> 4;
    const int brow = blockIdx.x * 128, bcol = blockIdx.y * 128;
    const int wr = w >> 1, wc = w & 1;
    const char* Ab = (const char*)A + (size_t)brow * 2048;
    const char* Bb = (const char*)Bt + (size_t)bcol * 2048;
    const int lrow = lane >> 2;
    const int lcol = (((lane & 3) ^ ((lane >> 3) & 3)) << 4);
    const int r0a = w * 32, r0b = w * 32 + 16;
    const size_t ga = (size_t)(r0a + lrow) * 2048 + lcol;
    const size_t gb = (size_t)(r0b + lrow) * 2048 + lcol;
    const int rsw = ((lg ^ ((lr >> 1) & 3)) << 4);

    f32x4 acc[4][4];
#pragma unroll
    for (int m = 0; m < 4; ++m)
#pragma unroll
        for (int n = 0; n < 4; ++n) acc[m][n] = (f32x4){0.f, 0.f, 0.f, 0.f};

    gl16(Ab + ga, (char*)As + r0a * 64);
    gl16(Ab + gb, (char*)As + r0b * 64);
    gl16(Bb + ga, (char*)Bs + r0a * 64);
    gl16(Bb + gb, (char*)Bs + r0b * 64);
    gl16(Ab + ga + 64, (char*)As + 8192 + r0a * 64);
    gl16(Ab + gb + 64, (char*)As + 8192 + r0b * 64);
    gl16(Bb + ga + 64, (char*)Bs + 8192 + r0a * 64);
    gl16(Bb + gb + 64, (char*)Bs + 8192 + r0b * 64);

    for (int tt = 0; tt < 32; ++tt) {
        if (tt < 31) {
            asm volatile("s_waitcnt vmcnt(4)" ::: "memory");
        } else {
            asm volatile("s_waitcnt vmcnt(0)" ::: "memory");
        }
        __builtin_amdgcn_s_barrier();
        __builtin_amdgcn_sched_barrier(0);
        if (tt < 30) {
            const int nb = (tt + 2) % 3;
            const size_t ko = (size_t)(tt + 2) * 64;
            char* Asn = (char*)As + nb * 8192;
            char* Bsn = (char*)Bs + nb * 8192;
            gl16(Ab + ga + ko, Asn + r0a * 64);
            gl16(Ab + gb + ko, Asn + r0b * 64);
            gl16(Bb + ga + ko, Bsn + r0a * 64);
            gl16(Bb + gb + ko, Bsn + r0b * 64);
        }
        const char* AsB = (const char*)As + (tt % 3) * 8192;
        const char* BsB = (const char*)Bs + (tt % 3) * 8192;
        bf16x8 af[4], bfr[4];
#pragma unroll
        for (int m = 0; m < 4; ++m)
            af[m] = *(const bf16x8*)(AsB + (wr * 64 + m * 16 + lr) * 64 + rsw);
#pragma unroll
        for (int n = 0; n < 4; ++n)
            bfr[n] = *(const bf16x8*)(BsB + (wc * 64 + n * 16 + lr) * 64 + rsw);
#pragma unroll
        for (int m = 0; m < 4; ++m)
#pragma unroll
            for (int n = 0; n < 4; ++n)
                acc[m][n] = __builtin_amdgcn_mfma_f32_16x16x32_bf16(af[m], bfr[n],
                                                                    acc[m][n], 0, 0, 0);
    }

#pragma unroll
    for (int n = 0; n < 4; ++n) {
        const int col = bcol + wc * 64 + n * 16 + lr;
        const float bb = bias0[col];
#pragma unroll
        for (int m = 0; m < 4; ++m)
#pragma unroll
            for (int r = 0; r < 4; ++r) {
                int row = brow + wr * 64 + m * 16 + 4 * lg + r;
                oc[(size_t)row * 1024 + col] = acc[m][n][r] + bb;
            }
    }
}

// ---------------------------------------------------------------- attention
// R12 version unchanged (v_exp_f32, 3-buffer depth-2, 32-row waves, V-hoist,
// C-init ALiBi, l-via-MFMA).
__global__ __launch_bounds__(256, 2) void attn_k(const u16* __restrict__ qg_,
                                                 const u16* __restrict__ kg_,
                                                 const u16* __restrict__ vg_,
                                                 u16* __restrict__ ao) {
    __shared__ __align__(16) u16 smem[24576];   // 48KB: K0|K1|K2|V0|V1|V2
    char* Kbase = (char*)smem;                  // 3 x 8KB
    char* Vbase = (char*)smem + 24576;          // 3 x 8KB
    const int t = threadIdx.x, w = t >> 6, lane = t & 63;
    const int lr = lane & 15, lg = lane >> 4;
    const int bid = blockIdx.y * 16 + blockIdx.x;
    const int qt = (bid >> 3) & 15;
    const int bh = ((bid >> 7) << 3) | (bid & 7);
    const int q0 = qt * 128, h = bh & 15, bb = bh >> 4;
    const float sl2 = exp2f(-0.5f * (float)(h + 1)) * 1.44269504f; // slope*log2e

    const int U0 = (w * 2) * 64 + lane, U1 = U0 + 64;
    const int rr0 = U0 >> 3, u0 = U0 & 7, rr1 = U1 >> 3, u1 = U1 & 7;
    const int koff0 = rr0 * 128 + ((u0 ^ (rr0 & 7)) << 4);
    const int koff1 = rr1 * 128 + ((u1 ^ (rr1 & 7)) << 4);
    const int voff0 = rr0 * 4096 + ((u0 ^ (rr0 & 7)) << 4);
    const int voff1 = rr1 * 4096 + ((u1 ^ (rr1 & 7)) << 4);
    const int lds0 = (w * 2) * 1024, lds1 = lds0 + 1024;

    const char* khead = (const char*)(kg_ + (size_t)bh * 2048 * 64);
    const char* vhead = (const char*)(vg_ + (size_t)bh * 64 * 2048);

    const char* qpA = (const char*)qg_ +
                      ((size_t)bh * 2048 + q0 + w * 32 + lr) * 128;
    bf16x8 qa0A = *(const bf16x8*)(qpA + lg * 16);
    bf16x8 qa1A = *(const bf16x8*)(qpA + 64 + lg * 16);
    bf16x8 qa0B = *(const bf16x8*)(qpA + 2048 + lg * 16);
    bf16x8 qa1B = *(const bf16x8*)(qpA + 2048 + 64 + lg * 16);

    gl16(khead + koff0, Kbase + lds0);
    gl16(khead + koff1, Kbase + lds1);
    gl16(vhead + voff0, Vbase + lds0);
    gl16(vhead + voff1, Vbase + lds1);
    gl16(khead + 8192 + koff0, Kbase + 8192 + lds0);
    gl16(khead + 8192 + koff1, Kbase + 8192 + lds1);
    gl16(vhead + 128 + voff0, Vbase + 8192 + lds0);
    gl16(vhead + 128 + voff1, Vbase + 8192 + lds1);

    f32x4 abF2[4];
#pragma unroll
    for (int n = 0; n < 4; ++n)
#pragma unroll
        for (int r = 0; r < 4; ++r)
            abF2[n][r] = sl2 * (float)(n * 16 + 4 * lg + r - 2047) - 16.0f;
    const float ainc = sl2 * 64.0f;
    f32x4 oaccA[4], oaccB[4];
#pragma unroll
    for (int nn = 0; nn < 4; ++nn) {
        oaccA[nn] = (f32x4){0.f, 0.f, 0.f, 0.f};
        oaccB[nn] = (f32x4){0.f, 0.f, 0.f, 0.f};
    }
#if HAVE_MFMA16
    f32x4 laccA = (f32x4){0.f, 0.f, 0.f, 0.f};
    f32x4 laccB = (f32x4){0.f, 0.f, 0.f, 0.f};
    const u32x2 onesb = {0x3F803F80u, 0x3F803F80u};   // 4 x bf16 1.0
    const s16x4 ones = __builtin_bit_cast(s16x4, onesb);
#else
    f32x4 l4A = (f32x4){0.f, 0.f, 0.f, 0.f};
    f32x4 l4B = (f32x4){0.f, 0.f, 0.f, 0.f};
    const int srcA = lr + ((lg & 1) << 5);
    const int srcB = srcA + 16;
    const bool hiHalf = (lg >> 1) != 0;
#endif

    for (int tt = 0; tt < 32; ++tt) {
        if (tt < 31) {
            asm volatile("s_waitcnt vmcnt(4)" ::: "memory");
        } else {
            asm volatile("s_waitcnt vmcnt(0)" ::: "memory");
        }
        __builtin_amdgcn_s_barrier();
        __builtin_amdgcn_sched_barrier(0);
        if (tt < 30) {
            const int nb = (tt + 2) % 3;
            const char* ks = khead + (size_t)(tt + 2) * 8192;
            const char* vs = vhead + (size_t)(tt + 2) * 128;
            gl16(ks + koff0, Kbase + nb * 8192 + lds0);
            gl16(ks + koff1, Kbase + nb * 8192 + lds1);
            gl16(vs + voff0, Vbase + nb * 8192 + lds0);
            gl16(vs + voff1, Vbase + nb * 8192 + lds1);
        }
        const char* Kc = Kbase + (tt % 3) * 8192;
        const char* Vc = Vbase + (tt % 3) * 8192;

        bf16x8 kf0[4], kf1[4];
#pragma unroll
        for (int n = 0; n < 4; ++n)
            kf0[n] = *(const bf16x8*)(Kc + (n * 16 + lr) * 128 +
                                      ((lg ^ (lr & 7)) << 4));
#pragma unroll
        for (int n = 0; n < 4; ++n)
            kf1[n] = *(const bf16x8*)(Kc + (n * 16 + lr) * 128 +
                                      (((4 + lg) ^ (lr & 7)) << 4));
#if HAVE_MFMA16
        s16x4 va_[4][4];
#pragma unroll
        for (int n = 0; n < 4; ++n)
#pragma unroll
            for (int nn = 0; nn < 4; ++nn)
                va_[n][nn] = *(const s16x4*)(Vc + (nn * 16 + lr) * 128 +
                                             (((2 * n + (lg >> 1)) ^ (lr & 7)) << 4) +
                                             ((lg & 1) << 3));
#endif

        f32x4 saA[4], saB[4];
        __builtin_amdgcn_s_setprio(1);
#pragma unroll
        for (int n = 0; n < 4; ++n) {
            saA[n] = __builtin_amdgcn_mfma_f32_16x16x32_bf16(kf0[n], qa0A, abF2[n],
                                                             0, 0, 0);
            saB[n] = __builtin_amdgcn_mfma_f32_16x16x32_bf16(kf0[n], qa0B, abF2[n],
                                                             0, 0, 0);
        }
#pragma unroll
        for (int n = 0; n < 4; ++n) {
            saA[n] = __builtin_amdgcn_mfma_f32_16x16x32_bf16(kf1[n], qa1A, saA[n],
                                                             0, 0, 0);
            saB[n] = __builtin_amdgcn_mfma_f32_16x16x32_bf16(kf1[n], qa1B, saB[n],
                                                             0, 0, 0);
        }
        __builtin_amdgcn_s_setprio(0);

#pragma unroll
        for (int n = 0; n < 4; ++n)
#pragma unroll
            for (int r = 0; r < 4; ++r) {
                saA[n][r] = fexp2(saA[n][r]);
                saB[n][r] = fexp2(saB[n][r]);
            }
#pragma unroll
        for (int n = 0; n < 4; ++n) abF2[n] += ainc;

#if HAVE_MFMA16
        s16x4 pnA[4], pnB[4];
#pragma unroll
        for (int n = 0; n < 4; ++n) {
            u32 lo, hi;
            asm("v_cvt_pk_bf16_f32 %0, %1, %2"
                : "=v"(lo) : "v"(saA[n][0]), "v"(saA[n][1]));
            asm("v_cvt_pk_bf16_f32 %0, %1, %2"
                : "=v"(hi) : "v"(saA[n][2]), "v"(saA[n][3]));
            u32x2 tmpa = {lo, hi};
            pnA[n] = __builtin_bit_cast(s16x4, tmpa);
            asm("v_cvt_pk_bf16_f32 %0, %1, %2"
                : "=v"(lo) : "v"(saB[n][0]), "v"(saB[n][1]));
            asm("v_cvt_pk_bf16_f32 %0, %1, %2"
                : "=v"(hi) : "v"(saB[n][2]), "v"(saB[n][3]));
            u32x2 tmpb = {lo, hi};
            pnB[n] = __builtin_bit_cast(s16x4, tmpb);
        }
        __builtin_amdgcn_s_setprio(1);
#pragma unroll
        for (int n = 0; n < 4; ++n) {
            laccA = __builtin_amdgcn_mfma_f32_16x16x16bf16_1k(ones, pnA[n],
                                                              laccA, 0, 0, 0);
            laccB = __builtin_amdgcn_mfma_f32_16x16x16bf16_1k(ones, pnB[n],
                                                              laccB, 0, 0, 0);
#pragma unroll
            for (int nn = 0; nn < 4; ++nn) {
                oaccA[nn] = __builtin_amdgcn_mfma_f32_16x16x16bf16_1k(va_[n][nn],
                                                                      pnA[n],
                                                                      oaccA[nn],
                                                                      0, 0, 0);
                oaccB[nn] = __builtin_amdgcn_mfma_f32_16x16x16bf16_1k(va_[n][nn],
                                                                      pnB[n],
                                                                      oaccB[nn],
                                                                      0, 0, 0);
            }
        }
        __builtin_amdgcn_s_setprio(0);
#else
#pragma unroll
        for (int n = 0; n < 4; ++n) { l4A += saA[n]; l4B += saB[n]; }
        u32 pk[8];
        u32x4 pb0, pb1;
#pragma unroll
        for (int n = 0; n < 4; ++n)
#pragma unroll
            for (int rp = 0; rp < 2; ++rp) {
                u32 rpk;
                asm("v_cvt_pk_bf16_f32 %0, %1, %2"
                    : "=v"(rpk) : "v"(saA[n][2 * rp]), "v"(saA[n][2 * rp + 1]));
                pk[n * 2 + rp] = rpk;
            }
#pragma unroll
        for (int g = 0; g < 4; ++g) {
            int src = (g < 2) ? srcA : srcB;
            u32 a0 = (u32)__shfl((int)pk[0 + (g & 1)], src);
            u32 a1 = (u32)__shfl((int)pk[2 + (g & 1)], src);
            u32 b0 = (u32)__shfl((int)pk[4 + (g & 1)], src);
            u32 b1 = (u32)__shfl((int)pk[6 + (g & 1)], src);
            pb0[g] = hiHalf ? a1 : a0;
            pb1[g] = hiHalf ? b1 : b0;
        }
        {
            bf16x8 pf0 = __builtin_bit_cast(bf16x8, pb0);
            bf16x8 pf1 = __builtin_bit_cast(bf16x8, pb1);
#pragma unroll
            for (int nn = 0; nn < 4; ++nn) {
                bf16x8 vf0 = *(const bf16x8*)(Vc + (nn * 16 + lr) * 128 +
                                              ((lg ^ (lr & 7)) << 4));
                oaccA[nn] = __builtin_amdgcn_mfma_f32_16x16x32_bf16(vf0, pf0,
                                                                    oaccA[nn], 0, 0, 0);
                bf16x8 vf1 = *(const bf16x8*)(Vc + (nn * 16 + lr) * 128 +
                                              (((4 + lg) ^ (lr & 7)) << 4));
                oaccA[nn] = __builtin_amdgcn_mfma_f32_16x16x32_bf16(vf1, pf1,
                                                                    oaccA[nn], 0, 0, 0);
            }
        }
#pragma unroll
        for (int n = 0; n < 4; ++n)
#pragma unroll
            for (int rp = 0; rp < 2; ++rp) {
                u32 rpk;
                asm("v_cvt_pk_bf16_f32 %0, %1, %2"
                    : "=v"(rpk) : "v"(saB[n][2 * rp]), "v"(saB[n][2 * rp + 1]));
                pk[n * 2 + rp] = rpk;
            }
#pragma unroll
        for (int g = 0; g < 4; ++g) {
            int src = (g < 2) ? srcA : srcB;
            u32 a0 = (u32)__shfl((int)pk[0 + (g & 1)], src);
            u32 a1 = (u32)__shfl((int)pk[2 + (g & 1)], src);
            u32 b0 = (u32)__shfl((int)pk[4 + (g & 1)], src);
            u32 b1 = (u32)__shfl((int)pk[6 + (g & 1)], src);
            pb0[g] = hiHalf ? a1 : a0;
            pb1[g] = hiHalf ? b1 : b0;
        }
        {
            bf16x8 pf0 = __builtin_bit_cast(bf16x8, pb0);
            bf16x8 pf1 = __builtin_bit_cast(bf16x8, pb1);
#pragma unroll
            for (int nn = 0; nn < 4; ++nn) {
                bf16x8 vf0 = *(const bf16x8*)(Vc + (nn * 16 + lr) * 128 +
                                              ((lg ^ (lr & 7)) << 4));
                oaccB[nn] = __builtin_amdgcn_mfma_f32_16x16x32_bf16(vf0, pf0,
                                                                    oaccB[nn], 0, 0, 0);
                bf16x8 vf1 = *(const bf16x8*)(Vc + (nn * 16 + lr) * 128 +
                                              (((4 + lg) ^ (lr & 7)) << 4));
                oaccB[nn] = __builtin_amdgcn_mfma_f32_16x16x32_bf16(vf1, pf1,
                                                                    oaccB[nn], 0, 0, 0);
            }
        }
#endif
    }

    __syncthreads();   // all waves done reading K/V buffers
#if HAVE_MFMA16
    const float linvA = 1.0f / laccA[0];
    const float linvB = 1.0f / laccB[0];
#else
    float lA = (l4A[0] + l4A[1]) + (l4A[2] + l4A[3]);
    lA += __shfl_xor(lA, 16);
    lA += __shfl_xor(lA, 32);
    float lB = (l4B[0] + l4B[1]) + (l4B[2] + l4B[3]);
    lB += __shfl_xor(lB, 16);
    lB += __shfl_xor(lB, 32);
    const float linvA = 1.0f / lA, linvB = 1.0f / lB;
#endif
    u16* ow = smem + w * (32 * 72);
#pragma unroll
    for (int nn = 0; nn < 4; ++nn)
#pragma unroll
        for (int r = 0; r < 4; ++r) {
            ow[lr * 72 + nn * 16 + 4 * lg + r] = f2bf(oaccA[nn][r] * linvA);
            ow[(16 + lr) * 72 + nn * 16 + 4 * lg + r] = f2bf(oaccB[nn][r] * linvB);
        }
    __syncthreads();
    const int q_ = lane >> 2, d0 = (lane & 3) << 4;
    const u16* orowA = smem + w * (32 * 72) + q_ * 72 + d0;
    const u16* orowB = orowA + 16 * 72;
    u16x8 a0 = *(const u16x8*)(orowA);
    u16x8 a1 = *(const u16x8*)(orowA + 8);
    u16x8 b0 = *(const u16x8*)(orowB);
    u16x8 b1 = *(const u16x8*)(orowB + 8);
    size_t gaddr = ((size_t)bb * 2048 + q0 + w * 32 + q_) * 1024 + h * 64 + d0;
    *(u16x8*)(ao + gaddr) = a0;
    *(u16x8*)(ao + gaddr + 8) = a1;
    *(u16x8*)(ao + gaddr + 16 * 1024) = b0;
    *(u16x8*)(ao + gaddr + 16 * 1024 + 8) = b1;
}

// ---------------------------------------------------------------- launch
extern "C" void kernel_launch(void* const* d_in, const int* in_sizes, int n_in,
                              void* d_out, int out_size, void* d_ws, size_t ws_size,
                              hipStream_t stream) {
    const float* x  = (const float*)d_in[0];
    const float* Wq = (const float*)d_in[1];
    const float* bq = (const float*)d_in[2];
    const float* Wk = (const float*)d_in[3];
    const float* bk = (const float*)d_in[4];
    const float* Wv = (const float*)d_in[5];
    const float* bv = (const float*)d_in[6];
    const float* Wo = (const float*)d_in[7];
    const float* bo = (const float*)d_in[8];

    const size_t MB = 1u << 20;
    if (ws_size < 40 * MB) return;
    char* ws = (char*)d_ws;
    u16* xb    = (u16*)(ws);             // 8MB  [4096][1024] bf16 (reused as ao)
    u16* wqkvt = (u16*)(ws + 8 * MB);    // 6MB  [3072][1024] = [Wq^T;Wk^T;Wv^T]
    u16* wot   = (u16*)(ws + 14 * MB);   // 2MB  Wo^T
    u16* qb    = (u16*)(ws + 16 * MB);   // 8MB  [32][2048][64]
    u16* kb    = (u16*)(ws + 24 * MB);   // 8MB  [32][2048][64]
    u16* vt    = (u16*)(ws + 32 * MB);   // 8MB  [32][64][2048]
    u16* ao    = xb;

    cvt_x_k<<<2048, 256, 0, stream>>>(x, xb);
    cvt_wT4_k<<<dim3(16, 16, 4), 256, 0, stream>>>(Wq, Wk, Wv, Wo, wqkvt, wot);

    gemm256_k<<<dim3(32, 12), 512, 0, stream>>>(xb, wqkvt, bq, bk, bv,
                                                qb, kb, vt);
    attn_k<<<dim3(16, 32), 256, 0, stream>>>(qb, kb, vt, ao);
    gemm_k<<<dim3(32, 8), 256, 0, stream>>>(ao, wot, bo, (float*)d_out);
}

// Round 14
// 127.478 us; speedup vs baseline: 1.0473x; 1.0473x over previous
//
#include <hip/hip_runtime.h>
#include <cstdint>
#include <cstddef>

typedef unsigned short u16;
typedef unsigned int u32;
typedef __bf16 bf16x8 __attribute__((ext_vector_type(8)));
typedef float f32x4 __attribute__((ext_vector_type(4)));
typedef u32 u32x2 __attribute__((ext_vector_type(2)));
typedef unsigned short u16x8 __attribute__((ext_vector_type(8)));
typedef short s16x4 __attribute__((ext_vector_type(4)));

// f32 -> bf16 round-to-nearest-even (finite inputs only)
__device__ __forceinline__ u16 f2bf(float f) {
    u32 u = __float_as_uint(f);
    u += 0x7fffu + ((u >> 16) & 1u);
    return (u16)(u >> 16);
}

// raw exp2: single v_exp_f32 (denormals flush to 0 = correct softmax tail)
__device__ __forceinline__ float fexp2(float x) {
    float r;
    asm("v_exp_f32 %0, %1" : "=v"(r) : "v"(x));
    return r;
}

// async global->LDS, 16B per lane. LDS ptr must be wave-uniform; HW adds lane*16.
__device__ __forceinline__ void gl16(const void* g, void* l) {
    __builtin_amdgcn_global_load_lds(
        (const __attribute__((address_space(1))) unsigned int*)g,
        (__attribute__((address_space(3))) unsigned int*)l, 16, 0, 0);
}

// ---------------------------------------------------------------- conversions
__global__ __launch_bounds__(256) void cvt_x_k(const float* __restrict__ x,
                                               u16* __restrict__ o) {
    int i = blockIdx.x * 256 + threadIdx.x;
    const float4* xv = (const float4*)x;
    float4 a = xv[2 * i], b = xv[2 * i + 1];
    ushort4 r0, r1;
    r0.x = f2bf(a.x); r0.y = f2bf(a.y); r0.z = f2bf(a.z); r0.w = f2bf(a.w);
    r1.x = f2bf(b.x); r1.y = f2bf(b.y); r1.z = f2bf(b.z); r1.w = f2bf(b.w);
    ((ushort4*)o)[2 * i] = r0;
    ((ushort4*)o)[2 * i + 1] = r1;
}

// All four W [1024][1024] f32 (k,n) -> bf16 (n,k) transposes in ONE launch.
__global__ __launch_bounds__(256) void cvt_wT4_k(const float* __restrict__ Wq,
                                                 const float* __restrict__ Wk,
                                                 const float* __restrict__ Wv,
                                                 const float* __restrict__ Wo,
                                                 u16* __restrict__ oqkv,
                                                 u16* __restrict__ oo) {
    __shared__ float tile[64][65];
    const int z = blockIdx.z;
    const float* W = (z == 0) ? Wq : (z == 1) ? Wk : (z == 2) ? Wv : Wo;
    u16* o = (z < 3) ? (oqkv + ((size_t)z << 20)) : oo;
    const int bx = blockIdx.x, by = blockIdx.y;
    const int t = threadIdx.x, tn = t & 63, tr = t >> 6;
#pragma unroll
    for (int r = 0; r < 16; ++r) {
        int kk = r * 4 + tr;
        tile[kk][tn] = W[(size_t)(by * 64 + kk) * 1024 + bx * 64 + tn];
    }
    __syncthreads();
#pragma unroll
    for (int r = 0; r < 16; ++r) {
        int nn = r * 4 + tr;
        o[(size_t)(bx * 64 + nn) * 1024 + by * 64 + tn] = f2bf(tile[tn][nn]);
    }
}

// ---------------------------------------------------------------- GEMM 128x128
// (R12-proven version, verbatim. R13's 128x256/512-thread variant regressed:
// grid 384 = 1.5 blocks/CU load imbalance.)
// 3-buffer depth-2 counted-vmcnt pipeline; zero-conflict both-sides swizzle.
// MODE 0: fused QKV epilogue; MODE 1: f32 out + bias.
template <int MODE>
__global__ __launch_bounds__(256) void gemm_k(
    const u16* __restrict__ A, const u16* __restrict__ Bt,
    const float* __restrict__ bias0, const float* __restrict__ bias1,
    const float* __restrict__ bias2,
    u16* __restrict__ oq, u16* __restrict__ ok_, u16* __restrict__ ov,
    float* __restrict__ oc) {
    __shared__ __align__(16) u16 As[3 * 128 * 32];   // 24KB
    __shared__ __align__(16) u16 Bs[3 * 128 * 32];   // 24KB
    const int t = threadIdx.x, w = t >> 6, lane = t & 63;
    const int lr = lane & 15, lg = lane >> 4;
    const int brow = blockIdx.x * 128, bcol = blockIdx.y * 128;
    const int wr = w >> 1, wc = w & 1;
    const char* Ab = (const char*)A + (size_t)brow * 2048;
    const char* Bb = (const char*)Bt + (size_t)bcol * 2048;
    const int lrow = lane >> 2;
    const int lcol = (((lane & 3) ^ ((lane >> 3) & 3)) << 4);
    const int r0a = w * 32, r0b = w * 32 + 16;
    const size_t ga = (size_t)(r0a + lrow) * 2048 + lcol;
    const size_t gb = (size_t)(r0b + lrow) * 2048 + lcol;
    const int rsw = ((lg ^ ((lr >> 1) & 3)) << 4);

    f32x4 acc[4][4];
#pragma unroll
    for (int m = 0; m < 4; ++m)
#pragma unroll
        for (int n = 0; n < 4; ++n) acc[m][n] = (f32x4){0.f, 0.f, 0.f, 0.f};

    gl16(Ab + ga, (char*)As + r0a * 64);
    gl16(Ab + gb, (char*)As + r0b * 64);
    gl16(Bb + ga, (char*)Bs + r0a * 64);
    gl16(Bb + gb, (char*)Bs + r0b * 64);
    gl16(Ab + ga + 64, (char*)As + 8192 + r0a * 64);
    gl16(Ab + gb + 64, (char*)As + 8192 + r0b * 64);
    gl16(Bb + ga + 64, (char*)Bs + 8192 + r0a * 64);
    gl16(Bb + gb + 64, (char*)Bs + 8192 + r0b * 64);

    for (int tt = 0; tt < 32; ++tt) {
        if (tt < 31) {
            asm volatile("s_waitcnt vmcnt(4)" ::: "memory");
        } else {
            asm volatile("s_waitcnt vmcnt(0)" ::: "memory");
        }
        __builtin_amdgcn_s_barrier();
        __builtin_amdgcn_sched_barrier(0);
        if (tt < 30) {
            const int nb = (tt + 2) % 3;
            const size_t ko = (size_t)(tt + 2) * 64;
            char* Asn = (char*)As + nb * 8192;
            char* Bsn = (char*)Bs + nb * 8192;
            gl16(Ab + ga + ko, Asn + r0a * 64);
            gl16(Ab + gb + ko, Asn + r0b * 64);
            gl16(Bb + ga + ko, Bsn + r0a * 64);
            gl16(Bb + gb + ko, Bsn + r0b * 64);
        }
        const char* AsB = (const char*)As + (tt % 3) * 8192;
        const char* BsB = (const char*)Bs + (tt % 3) * 8192;
        bf16x8 af[4], bfr[4];
#pragma unroll
        for (int m = 0; m < 4; ++m)
            af[m] = *(const bf16x8*)(AsB + (wr * 64 + m * 16 + lr) * 64 + rsw);
#pragma unroll
        for (int n = 0; n < 4; ++n)
            bfr[n] = *(const bf16x8*)(BsB + (wc * 64 + n * 16 + lr) * 64 + rsw);
#pragma unroll
        for (int m = 0; m < 4; ++m)
#pragma unroll
            for (int n = 0; n < 4; ++n)
                acc[m][n] = __builtin_amdgcn_mfma_f32_16x16x32_bf16(af[m], bfr[n],
                                                                    acc[m][n], 0, 0, 0);
    }

    const float QSCALE = 0.125f * 1.44269504f;
#pragma unroll
    for (int n = 0; n < 4; ++n) {
        const int col = bcol + wc * 64 + n * 16 + lr;
        if (MODE == 0) {
#pragma unroll
            for (int m = 0; m < 4; ++m)
#pragma unroll
                for (int r = 0; r < 4; ++r) {
                    int row = brow + wr * 64 + m * 16 + 4 * lg + r;
                    int b = row >> 11, l = row & 2047;
                    float val = acc[m][n][r];
                    if (col < 1024) {
                        int hh = col >> 6, d = col & 63;
                        oq[(((size_t)b * 16 + hh) * 2048 + l) * 64 + d] =
                            f2bf((val + bias0[col]) * QSCALE);
                    } else if (col < 2048) {
                        int c = col - 1024, hh = c >> 6, d = c & 63;
                        ok_[(((size_t)b * 16 + hh) * 2048 + l) * 64 + d] =
                            f2bf(val + bias1[c]);
                    } else {
                        int c = col - 2048, hh = c >> 6, d = c & 63;
                        ov[(((size_t)b * 16 + hh) * 64 + d) * 2048 + l] =
                            f2bf(val + bias2[c]);
                    }
                }
        } else {
            const float bb = bias0[col];
#pragma unroll
            for (int m = 0; m < 4; ++m)
#pragma unroll
                for (int r = 0; r < 4; ++r) {
                    int row = brow + wr * 64 + m * 16 + 4 * lg + r;
                    oc[(size_t)row * 1024 + col] = acc[m][n][r] + bb;
                }
        }
    }
}

// ---------------------------------------------------------------- attention
// KVBLK=128: 16 phases (half the barriers of KVBLK=64), 2-buffer depth-1
// (stage(t+1) at phase top hides under the 2x-long compute). 64KB LDS ->
// 2 blocks/CU (m132). 32-row waves (A,B sub-blocks share every K/V frag).
// MAX-FREE softmax (full exponent shift in MFMA C-init, += sl2*128/tile).
// PV + l via 16x16x16 MFMA (B-frag == S^T C-layout; ones-row for l).
__global__ __launch_bounds__(256, 2) void attn_k(const u16* __restrict__ qg_,
                                                 const u16* __restrict__ kg_,
                                                 const u16* __restrict__ vg_,
                                                 u16* __restrict__ ao) {
    __shared__ __align__(16) u16 smem[32768];   // 64KB: K0|K1 | V0|V1 (16KB ea)
    char* Kbase = (char*)smem;                  // 2 x 16384
    char* Vbase = (char*)smem + 32768;          // 2 x 16384
    const int t = threadIdx.x, w = t >> 6, lane = t & 63;
    const int lr = lane & 15, lg = lane >> 4;
    const int bid = blockIdx.y * 16 + blockIdx.x;
    const int qt = (bid >> 3) & 15;
    const int bh = ((bid >> 7) << 3) | (bid & 7);
    const int q0 = qt * 128, h = bh & 15, bb = bh >> 4;
    const float sl2 = exp2f(-0.5f * (float)(h + 1)) * 1.44269504f; // slope*log2e

    const char* khead = (const char*)(kg_ + (size_t)bh * 2048 * 64);
    const char* vhead = (const char*)(vg_ + (size_t)bh * 64 * 2048);

    // K staging: wave w stages rows 32w..32w+31 (4 gl16 x 8 rows of 128B).
    // LDS[r][g] = G[r][g ^ (r&7)], g in 16B granules.
    const int krow = lane >> 3, ku = lane & 7;
    const int kso = (w * 32 + krow) * 128 + ((ku ^ (krow & 7)) << 4);
    const int kdo = w * 4096;
    // V staging: wave w stages d-rows 16w..16w+15 (4 gl16 x 4 rows of 256B).
    // Source row stride 4096B (global vt); LDS[d][g] = G[d][g ^ (d&7)].
    const int vrow = lane >> 4, vgr = lane & 15;
    int vso[4];
#pragma unroll
    for (int i = 0; i < 4; ++i)
        vso[i] = (w * 16 + 4 * i + vrow) * 4096 +
                 ((vgr ^ ((4 * i + vrow) & 7)) << 4);
    const int vdo = w * 4096;

    // Q fragments straight from global, 32 rows per wave
    const char* qpA = (const char*)qg_ +
                      ((size_t)bh * 2048 + q0 + w * 32 + lr) * 128;
    bf16x8 qa0A = *(const bf16x8*)(qpA + lg * 16);
    bf16x8 qa1A = *(const bf16x8*)(qpA + 64 + lg * 16);
    bf16x8 qa0B = *(const bf16x8*)(qpA + 2048 + lg * 16);
    bf16x8 qa1B = *(const bf16x8*)(qpA + 2048 + 64 + lg * 16);

    // C-init carries whole exponent shift: sl2*(jloc-2047)-16, jloc=n*16+4lg+r
    f32x4 abF2[8];
#pragma unroll
    for (int n = 0; n < 8; ++n)
#pragma unroll
        for (int r = 0; r < 4; ++r)
            abF2[n][r] = sl2 * (float)(n * 16 + 4 * lg + r - 2047) - 16.0f;
    const float ainc = sl2 * 128.0f;
    f32x4 oaccA[4], oaccB[4];
#pragma unroll
    for (int nn = 0; nn < 4; ++nn) {
        oaccA[nn] = (f32x4){0.f, 0.f, 0.f, 0.f};
        oaccB[nn] = (f32x4){0.f, 0.f, 0.f, 0.f};
    }
    f32x4 laccA = (f32x4){0.f, 0.f, 0.f, 0.f};
    f32x4 laccB = (f32x4){0.f, 0.f, 0.f, 0.f};
    const u32x2 onesb = {0x3F803F80u, 0x3F803F80u};   // 4 x bf16 1.0
    const s16x4 ones = __builtin_bit_cast(s16x4, onesb);

    // prologue: stage tile 0 into buffer 0 (8 gl16/wave), drain, sync
    {
        char* kd = Kbase + kdo;
        char* vd = Vbase + vdo;
#pragma unroll
        for (int i = 0; i < 4; ++i) gl16(khead + kso + i * 1024, kd + i * 1024);
#pragma unroll
        for (int i = 0; i < 4; ++i) gl16(vhead + vso[i], vd + i * 1024);
    }
    asm volatile("s_waitcnt vmcnt(0)" ::: "memory");
    __builtin_amdgcn_s_barrier();
    __builtin_amdgcn_sched_barrier(0);

    for (int tt = 0; tt < 16; ++tt) {
        if (tt < 15) {   // stage next tile into the other buffer (issue-early)
            const char* ks = khead + (size_t)(tt + 1) * 16384;
            const char* vs = vhead + (size_t)(tt + 1) * 256;
            char* kd = Kbase + ((tt + 1) & 1) * 16384 + kdo;
            char* vd = Vbase + ((tt + 1) & 1) * 16384 + vdo;
#pragma unroll
            for (int i = 0; i < 4; ++i) gl16(ks + kso + i * 1024, kd + i * 1024);
#pragma unroll
            for (int i = 0; i < 4; ++i) gl16(vs + vso[i], vd + i * 1024);
        }
        const char* Kc = Kbase + (tt & 1) * 16384;
        const char* Vc = Vbase + (tt & 1) * 16384;

        // S^T = mfma(K, Q) + C-init bias: 128 j-rows per phase
        f32x4 saA[8], saB[8];
        __builtin_amdgcn_s_setprio(1);
#pragma unroll
        for (int n = 0; n < 8; ++n) {
            bf16x8 kf = *(const bf16x8*)(Kc + (n * 16 + lr) * 128 +
                                         ((lg ^ (lr & 7)) << 4));
            saA[n] = __builtin_amdgcn_mfma_f32_16x16x32_bf16(kf, qa0A, abF2[n],
                                                             0, 0, 0);
            saB[n] = __builtin_amdgcn_mfma_f32_16x16x32_bf16(kf, qa0B, abF2[n],
                                                             0, 0, 0);
        }
#pragma unroll
        for (int n = 0; n < 8; ++n) {
            bf16x8 kf = *(const bf16x8*)(Kc + (n * 16 + lr) * 128 +
                                         (((4 + lg) ^ (lr & 7)) << 4));
            saA[n] = __builtin_amdgcn_mfma_f32_16x16x32_bf16(kf, qa1A, saA[n],
                                                             0, 0, 0);
            saB[n] = __builtin_amdgcn_mfma_f32_16x16x32_bf16(kf, qa1B, saB[n],
                                                             0, 0, 0);
        }
        __builtin_amdgcn_s_setprio(0);

        // max-free softmax: P = exp2(sa)
#pragma unroll
        for (int n = 0; n < 8; ++n)
#pragma unroll
            for (int r = 0; r < 4; ++r) {
                saA[n][r] = fexp2(saA[n][r]);
                saB[n][r] = fexp2(saB[n][r]);
            }
#pragma unroll
        for (int n = 0; n < 8; ++n) abF2[n] += ainc;

        // PV + l per 16-j slice (V rows are 256B; granule = (2n+(lg>>1))^(lr&7))
        __builtin_amdgcn_s_setprio(1);
#pragma unroll
        for (int n = 0; n < 8; ++n) {
            u32 lo, hi;
            asm("v_cvt_pk_bf16_f32 %0, %1, %2"
                : "=v"(lo) : "v"(saA[n][0]), "v"(saA[n][1]));
            asm("v_cvt_pk_bf16_f32 %0, %1, %2"
                : "=v"(hi) : "v"(saA[n][2]), "v"(saA[n][3]));
            u32x2 tmpa = {lo, hi};
            s16x4 pnA = __builtin_bit_cast(s16x4, tmpa);
            asm("v_cvt_pk_bf16_f32 %0, %1, %2"
                : "=v"(lo) : "v"(saB[n][0]), "v"(saB[n][1]));
            asm("v_cvt_pk_bf16_f32 %0, %1, %2"
                : "=v"(hi) : "v"(saB[n][2]), "v"(saB[n][3]));
            u32x2 tmpb = {lo, hi};
            s16x4 pnB = __builtin_bit_cast(s16x4, tmpb);
            laccA = __builtin_amdgcn_mfma_f32_16x16x16bf16_1k(ones, pnA,
                                                              laccA, 0, 0, 0);
            laccB = __builtin_amdgcn_mfma_f32_16x16x16bf16_1k(ones, pnB,
                                                              laccB, 0, 0, 0);
#pragma unroll
            for (int nn = 0; nn < 4; ++nn) {
                s16x4 va = *(const s16x4*)(Vc + (nn * 16 + lr) * 256 +
                                           (((2 * n + (lg >> 1)) ^ (lr & 7)) << 4) +
                                           ((lg & 1) << 3));
                oaccA[nn] = __builtin_amdgcn_mfma_f32_16x16x16bf16_1k(va, pnA,
                                                                      oaccA[nn],
                                                                      0, 0, 0);
                oaccB[nn] = __builtin_amdgcn_mfma_f32_16x16x16bf16_1k(va, pnB,
                                                                      oaccB[nn],
                                                                      0, 0, 0);
            }
        }
        __builtin_amdgcn_s_setprio(0);

        // drain next-tile staging (hidden under the long compute), then sync
        asm volatile("s_waitcnt vmcnt(0)" ::: "memory");
        __builtin_amdgcn_s_barrier();
        __builtin_amdgcn_sched_barrier(0);
    }

    // epilogue: normalize, transpose O^T -> O via per-wave LDS scratch
    const float linvA = 1.0f / laccA[0];
    const float linvB = 1.0f / laccB[0];
    u16* ow = smem + w * (32 * 72);
#pragma unroll
    for (int nn = 0; nn < 4; ++nn)
#pragma unroll
        for (int r = 0; r < 4; ++r) {
            ow[lr * 72 + nn * 16 + 4 * lg + r] = f2bf(oaccA[nn][r] * linvA);
            ow[(16 + lr) * 72 + nn * 16 + 4 * lg + r] = f2bf(oaccB[nn][r] * linvB);
        }
    __syncthreads();
    const int q_ = lane >> 2, d0 = (lane & 3) << 4;
    const u16* orowA = smem + w * (32 * 72) + q_ * 72 + d0;
    const u16* orowB = orowA + 16 * 72;
    u16x8 a0 = *(const u16x8*)(orowA);
    u16x8 a1 = *(const u16x8*)(orowA + 8);
    u16x8 b0 = *(const u16x8*)(orowB);
    u16x8 b1 = *(const u16x8*)(orowB + 8);
    size_t gaddr = ((size_t)bb * 2048 + q0 + w * 32 + q_) * 1024 + h * 64 + d0;
    *(u16x8*)(ao + gaddr) = a0;
    *(u16x8*)(ao + gaddr + 8) = a1;
    *(u16x8*)(ao + gaddr + 16 * 1024) = b0;
    *(u16x8*)(ao + gaddr + 16 * 1024 + 8) = b1;
}

// ---------------------------------------------------------------- launch
extern "C" void kernel_launch(void* const* d_in, const int* in_sizes, int n_in,
                              void* d_out, int out_size, void* d_ws, size_t ws_size,
                              hipStream_t stream) {
    const float* x  = (const float*)d_in[0];
    const float* Wq = (const float*)d_in[1];
    const float* bq = (const float*)d_in[2];
    const float* Wk = (const float*)d_in[3];
    const float* bk = (const float*)d_in[4];
    const float* Wv = (const float*)d_in[5];
    const float* bv = (const float*)d_in[6];
    const float* Wo = (const float*)d_in[7];
    const float* bo = (const float*)d_in[8];

    const size_t MB = 1u << 20;
    if (ws_size < 40 * MB) return;
    char* ws = (char*)d_ws;
    u16* xb    = (u16*)(ws);             // 8MB  [4096][1024] bf16 (reused as ao)
    u16* wqkvt = (u16*)(ws + 8 * MB);    // 6MB  [3072][1024] = [Wq^T;Wk^T;Wv^T]
    u16* wot   = (u16*)(ws + 14 * MB);   // 2MB  Wo^T
    u16* qb    = (u16*)(ws + 16 * MB);   // 8MB  [32][2048][64]
    u16* kb    = (u16*)(ws + 24 * MB);   // 8MB  [32][2048][64]
    u16* vt    = (u16*)(ws + 32 * MB);   // 8MB  [32][64][2048]
    u16* ao    = xb;

    cvt_x_k<<<2048, 256, 0, stream>>>(x, xb);
    cvt_wT4_k<<<dim3(16, 16, 4), 256, 0, stream>>>(Wq, Wk, Wv, Wo, wqkvt, wot);

    gemm_k<0><<<dim3(32, 24), 256, 0, stream>>>(xb, wqkvt, bq, bk, bv,
                                                qb, kb, vt, nullptr);
    attn_k<<<dim3(16, 32), 256, 0, stream>>>(qb, kb, vt, ao);
    gemm_k<1><<<dim3(32, 8), 256, 0, stream>>>(ao, wot, bo, nullptr, nullptr,
                                               nullptr, nullptr, nullptr,
                                               (float*)d_out);
}

// Round 15
// 113.317 us; speedup vs baseline: 1.1781x; 1.1250x over previous
//
#include <hip/hip_runtime.h>
#include <cstdint>
#include <cstddef>

typedef unsigned short u16;
typedef unsigned int u32;
typedef __bf16 bf16x8 __attribute__((ext_vector_type(8)));
typedef float f32x4 __attribute__((ext_vector_type(4)));
typedef u32 u32x2 __attribute__((ext_vector_type(2)));
typedef unsigned short u16x8 __attribute__((ext_vector_type(8)));
typedef short s16x4 __attribute__((ext_vector_type(4)));

// f32 -> bf16 round-to-nearest-even (finite inputs only)
__device__ __forceinline__ u16 f2bf(float f) {
    u32 u = __float_as_uint(f);
    u += 0x7fffu + ((u >> 16) & 1u);
    return (u16)(u >> 16);
}

// raw exp2: single v_exp_f32 (denormals flush to 0 = correct softmax tail)
__device__ __forceinline__ float fexp2(float x) {
    float r;
    asm("v_exp_f32 %0, %1" : "=v"(r) : "v"(x));
    return r;
}

// async global->LDS, 16B per lane. LDS ptr must be wave-uniform; HW adds lane*16.
__device__ __forceinline__ void gl16(const void* g, void* l) {
    __builtin_amdgcn_global_load_lds(
        (const __attribute__((address_space(1))) unsigned int*)g,
        (__attribute__((address_space(3))) unsigned int*)l, 16, 0, 0);
}

// ---------------------------------------------------------------- conversions
// z 0..3: W [1024][1024] f32 (k,n) -> bf16 (n,k). z 4..11: x f32 -> bf16 chunks.
__global__ __launch_bounds__(256) void cvt_all_k(const float* __restrict__ Wq,
                                                 const float* __restrict__ Wk,
                                                 const float* __restrict__ Wv,
                                                 const float* __restrict__ Wo,
                                                 const float* __restrict__ x,
                                                 u16* __restrict__ oqkv,
                                                 u16* __restrict__ oo,
                                                 u16* __restrict__ ox) {
    const int z = blockIdx.z;
    const int bx = blockIdx.x, by = blockIdx.y;
    const int t = threadIdx.x;
    if (z >= 4) {   // x conversion: 8 f32 per thread
        int i = ((z - 4) * 256 + by * 16 + bx) * 256 + t;
        const float4* xv = (const float4*)x;
        float4 a = xv[2 * i], b = xv[2 * i + 1];
        ushort4 r0, r1;
        r0.x = f2bf(a.x); r0.y = f2bf(a.y); r0.z = f2bf(a.z); r0.w = f2bf(a.w);
        r1.x = f2bf(b.x); r1.y = f2bf(b.y); r1.z = f2bf(b.z); r1.w = f2bf(b.w);
        ((ushort4*)ox)[2 * i] = r0;
        ((ushort4*)ox)[2 * i + 1] = r1;
        return;
    }
    __shared__ float tile[64][65];
    const float* W = (z == 0) ? Wq : (z == 1) ? Wk : (z == 2) ? Wv : Wo;
    u16* o = (z < 3) ? (oqkv + ((size_t)z << 20)) : oo;
    const int tn = t & 63, tr = t >> 6;
#pragma unroll
    for (int r = 0; r < 16; ++r) {
        int kk = r * 4 + tr;
        tile[kk][tn] = W[(size_t)(by * 64 + kk) * 1024 + bx * 64 + tn];
    }
    __syncthreads();
#pragma unroll
    for (int r = 0; r < 16; ++r) {
        int nn = r * 4 + tr;
        o[(size_t)(bx * 64 + nn) * 1024 + by * 64 + tn] = f2bf(tile[tn][nn]);
    }
}

// ---------------------------------------------------------------- GEMM 128x128
// 3-buffer depth-2 counted-vmcnt pipeline; zero-conflict both-sides swizzle.
// MODE 0: fused QKV epilogue. V-blocks (bcol>=2048) store via an LDS
//   transpose -> coalesced 128B runs (the 2B/4KB-stride scatter was ~16.7M
//   store transactions, the hidden cost). MODE 1: f32 out + bias.
template <int MODE>
__global__ __launch_bounds__(256) void gemm_k(
    const u16* __restrict__ A, const u16* __restrict__ Bt,
    const float* __restrict__ bias0, const float* __restrict__ bias1,
    const float* __restrict__ bias2,
    u16* __restrict__ oq, u16* __restrict__ ok_, u16* __restrict__ ov,
    float* __restrict__ oc) {
    __shared__ __align__(16) u16 sh[2 * 3 * 128 * 32];   // 48KB total
    u16* As = sh;
    u16* Bs = sh + 3 * 128 * 32;
    const int t = threadIdx.x, w = t >> 6, lane = t & 63;
    const int lr = lane & 15, lg = lane >> 4;
    const int brow = blockIdx.x * 128, bcol = blockIdx.y * 128;
    const int wr = w >> 1, wc = w & 1;
    const char* Ab = (const char*)A + (size_t)brow * 2048;
    const char* Bb = (const char*)Bt + (size_t)bcol * 2048;
    const int lrow = lane >> 2;
    const int lcol = (((lane & 3) ^ ((lane >> 3) & 3)) << 4);
    const int r0a = w * 32, r0b = w * 32 + 16;
    const size_t ga = (size_t)(r0a + lrow) * 2048 + lcol;
    const size_t gb = (size_t)(r0b + lrow) * 2048 + lcol;
    const int rsw = ((lg ^ ((lr >> 1) & 3)) << 4);

    f32x4 acc[4][4];
#pragma unroll
    for (int m = 0; m < 4; ++m)
#pragma unroll
        for (int n = 0; n < 4; ++n) acc[m][n] = (f32x4){0.f, 0.f, 0.f, 0.f};

    gl16(Ab + ga, (char*)As + r0a * 64);
    gl16(Ab + gb, (char*)As + r0b * 64);
    gl16(Bb + ga, (char*)Bs + r0a * 64);
    gl16(Bb + gb, (char*)Bs + r0b * 64);
    gl16(Ab + ga + 64, (char*)As + 8192 + r0a * 64);
    gl16(Ab + gb + 64, (char*)As + 8192 + r0b * 64);
    gl16(Bb + ga + 64, (char*)Bs + 8192 + r0a * 64);
    gl16(Bb + gb + 64, (char*)Bs + 8192 + r0b * 64);

    for (int tt = 0; tt < 32; ++tt) {
        if (tt < 31) {
            asm volatile("s_waitcnt vmcnt(4)" ::: "memory");
        } else {
            asm volatile("s_waitcnt vmcnt(0)" ::: "memory");
        }
        __builtin_amdgcn_s_barrier();
        __builtin_amdgcn_sched_barrier(0);
        if (tt < 30) {
            const int nb = (tt + 2) % 3;
            const size_t ko = (size_t)(tt + 2) * 64;
            char* Asn = (char*)As + nb * 8192;
            char* Bsn = (char*)Bs + nb * 8192;
            gl16(Ab + ga + ko, Asn + r0a * 64);
            gl16(Ab + gb + ko, Asn + r0b * 64);
            gl16(Bb + ga + ko, Bsn + r0a * 64);
            gl16(Bb + gb + ko, Bsn + r0b * 64);
        }
        const char* AsB = (const char*)As + (tt % 3) * 8192;
        const char* BsB = (const char*)Bs + (tt % 3) * 8192;
        bf16x8 af[4], bfr[4];
#pragma unroll
        for (int m = 0; m < 4; ++m)
            af[m] = *(const bf16x8*)(AsB + (wr * 64 + m * 16 + lr) * 64 + rsw);
#pragma unroll
        for (int n = 0; n < 4; ++n)
            bfr[n] = *(const bf16x8*)(BsB + (wc * 64 + n * 16 + lr) * 64 + rsw);
#pragma unroll
        for (int m = 0; m < 4; ++m)
#pragma unroll
            for (int n = 0; n < 4; ++n)
                acc[m][n] = __builtin_amdgcn_mfma_f32_16x16x32_bf16(af[m], bfr[n],
                                                                    acc[m][n], 0, 0, 0);
    }

    const float QSCALE = 0.125f * 1.44269504f;
    if (MODE == 0 && bcol >= 2048) {
        // V block: transpose via LDS (rows stride 136 u16 = 272B, 16B-aligned)
        // then store coalesced 128B runs into vt [b*1024 + c][l].
        const int b = brow >> 11, l0 = brow & 2047;
        __syncthreads();   // all waves done with K/V LDS buffers
#pragma unroll
        for (int n = 0; n < 4; ++n) {
            const int cl = wc * 64 + n * 16 + lr;
            const float bb2 = bias2[bcol - 2048 + cl];
#pragma unroll
            for (int m = 0; m < 4; ++m)
#pragma unroll
                for (int r = 0; r < 4; ++r) {
                    int ll = wr * 64 + m * 16 + 4 * lg + r;
                    sh[cl * 136 + ll] = f2bf(acc[m][n][r] + bb2);
                }
        }
        __syncthreads();
        const int rr = t >> 1, hf = t & 1;
        const u16* src = sh + rr * 136 + hf * 64;
        u16* dst = ov + ((size_t)b * 1024 + (bcol - 2048) + rr) * 2048 +
                   l0 + hf * 64;
#pragma unroll
        for (int i = 0; i < 8; ++i)
            *(u16x8*)(dst + i * 8) = *(const u16x8*)(src + i * 8);
        return;
    }
#pragma unroll
    for (int n = 0; n < 4; ++n) {
        const int col = bcol + wc * 64 + n * 16 + lr;
        if (MODE == 0) {
#pragma unroll
            for (int m = 0; m < 4; ++m)
#pragma unroll
                for (int r = 0; r < 4; ++r) {
                    int row = brow + wr * 64 + m * 16 + 4 * lg + r;
                    int b = row >> 11, l = row & 2047;
                    float val = acc[m][n][r];
                    if (col < 1024) {
                        int hh = col >> 6, d = col & 63;
                        oq[(((size_t)b * 16 + hh) * 2048 + l) * 64 + d] =
                            f2bf((val + bias0[col]) * QSCALE);
                    } else {
                        int c = col - 1024, hh = c >> 6, d = c & 63;
                        ok_[(((size_t)b * 16 + hh) * 2048 + l) * 64 + d] =
                            f2bf(val + bias1[c]);
                    }
                }
        } else {
            const float bb = bias0[col];
#pragma unroll
            for (int m = 0; m < 4; ++m)
#pragma unroll
                for (int r = 0; r < 4; ++r) {
                    int row = brow + wr * 64 + m * 16 + 4 * lg + r;
                    oc[(size_t)row * 1024 + col] = acc[m][n][r] + bb;
                }
        }
    }
}

// ---------------------------------------------------------------- attention
// (R14 version unchanged: KVBLK=128, 2-buffer depth-1, 32-row waves,
// max-free softmax in MFMA C-init, PV+l via 16x16x16 MFMA, v_exp_f32.)
__global__ __launch_bounds__(256, 2) void attn_k(const u16* __restrict__ qg_,
                                                 const u16* __restrict__ kg_,
                                                 const u16* __restrict__ vg_,
                                                 u16* __restrict__ ao) {
    __shared__ __align__(16) u16 smem[32768];   // 64KB: K0|K1 | V0|V1 (16KB ea)
    char* Kbase = (char*)smem;                  // 2 x 16384
    char* Vbase = (char*)smem + 32768;          // 2 x 16384
    const int t = threadIdx.x, w = t >> 6, lane = t & 63;
    const int lr = lane & 15, lg = lane >> 4;
    const int bid = blockIdx.y * 16 + blockIdx.x;
    const int qt = (bid >> 3) & 15;
    const int bh = ((bid >> 7) << 3) | (bid & 7);
    const int q0 = qt * 128, h = bh & 15, bb = bh >> 4;
    const float sl2 = exp2f(-0.5f * (float)(h + 1)) * 1.44269504f; // slope*log2e

    const char* khead = (const char*)(kg_ + (size_t)bh * 2048 * 64);
    const char* vhead = (const char*)(vg_ + (size_t)bh * 64 * 2048);

    const int krow = lane >> 3, ku = lane & 7;
    const int kso = (w * 32 + krow) * 128 + ((ku ^ (krow & 7)) << 4);
    const int kdo = w * 4096;
    const int vrow = lane >> 4, vgr = lane & 15;
    int vso[4];
#pragma unroll
    for (int i = 0; i < 4; ++i)
        vso[i] = (w * 16 + 4 * i + vrow) * 4096 +
                 ((vgr ^ ((4 * i + vrow) & 7)) << 4);
    const int vdo = w * 4096;

    const char* qpA = (const char*)qg_ +
                      ((size_t)bh * 2048 + q0 + w * 32 + lr) * 128;
    bf16x8 qa0A = *(const bf16x8*)(qpA + lg * 16);
    bf16x8 qa1A = *(const bf16x8*)(qpA + 64 + lg * 16);
    bf16x8 qa0B = *(const bf16x8*)(qpA + 2048 + lg * 16);
    bf16x8 qa1B = *(const bf16x8*)(qpA + 2048 + 64 + lg * 16);

    f32x4 abF2[8];
#pragma unroll
    for (int n = 0; n < 8; ++n)
#pragma unroll
        for (int r = 0; r < 4; ++r)
            abF2[n][r] = sl2 * (float)(n * 16 + 4 * lg + r - 2047) - 16.0f;
    const float ainc = sl2 * 128.0f;
    f32x4 oaccA[4], oaccB[4];
#pragma unroll
    for (int nn = 0; nn < 4; ++nn) {
        oaccA[nn] = (f32x4){0.f, 0.f, 0.f, 0.f};
        oaccB[nn] = (f32x4){0.f, 0.f, 0.f, 0.f};
    }
    f32x4 laccA = (f32x4){0.f, 0.f, 0.f, 0.f};
    f32x4 laccB = (f32x4){0.f, 0.f, 0.f, 0.f};
    const u32x2 onesb = {0x3F803F80u, 0x3F803F80u};   // 4 x bf16 1.0
    const s16x4 ones = __builtin_bit_cast(s16x4, onesb);

    {
        char* kd = Kbase + kdo;
        char* vd = Vbase + vdo;
#pragma unroll
        for (int i = 0; i < 4; ++i) gl16(khead + kso + i * 1024, kd + i * 1024);
#pragma unroll
        for (int i = 0; i < 4; ++i) gl16(vhead + vso[i], vd + i * 1024);
    }
    asm volatile("s_waitcnt vmcnt(0)" ::: "memory");
    __builtin_amdgcn_s_barrier();
    __builtin_amdgcn_sched_barrier(0);

    for (int tt = 0; tt < 16; ++tt) {
        if (tt < 15) {
            const char* ks = khead + (size_t)(tt + 1) * 16384;
            const char* vs = vhead + (size_t)(tt + 1) * 256;
            char* kd = Kbase + ((tt + 1) & 1) * 16384 + kdo;
            char* vd = Vbase + ((tt + 1) & 1) * 16384 + vdo;
#pragma unroll
            for (int i = 0; i < 4; ++i) gl16(ks + kso + i * 1024, kd + i * 1024);
#pragma unroll
            for (int i = 0; i < 4; ++i) gl16(vs + vso[i], vd + i * 1024);
        }
        const char* Kc = Kbase + (tt & 1) * 16384;
        const char* Vc = Vbase + (tt & 1) * 16384;

        f32x4 saA[8], saB[8];
        __builtin_amdgcn_s_setprio(1);
#pragma unroll
        for (int n = 0; n < 8; ++n) {
            bf16x8 kf = *(const bf16x8*)(Kc + (n * 16 + lr) * 128 +
                                         ((lg ^ (lr & 7)) << 4));
            saA[n] = __builtin_amdgcn_mfma_f32_16x16x32_bf16(kf, qa0A, abF2[n],
                                                             0, 0, 0);
            saB[n] = __builtin_amdgcn_mfma_f32_16x16x32_bf16(kf, qa0B, abF2[n],
                                                             0, 0, 0);
        }
#pragma unroll
        for (int n = 0; n < 8; ++n) {
            bf16x8 kf = *(const bf16x8*)(Kc + (n * 16 + lr) * 128 +
                                         (((4 + lg) ^ (lr & 7)) << 4));
            saA[n] = __builtin_amdgcn_mfma_f32_16x16x32_bf16(kf, qa1A, saA[n],
                                                             0, 0, 0);
            saB[n] = __builtin_amdgcn_mfma_f32_16x16x32_bf16(kf, qa1B, saB[n],
                                                             0, 0, 0);
        }
        __builtin_amdgcn_s_setprio(0);

#pragma unroll
        for (int n = 0; n < 8; ++n)
#pragma unroll
            for (int r = 0; r < 4; ++r) {
                saA[n][r] = fexp2(saA[n][r]);
                saB[n][r] = fexp2(saB[n][r]);
            }
#pragma unroll
        for (int n = 0; n < 8; ++n) abF2[n] += ainc;

        __builtin_amdgcn_s_setprio(1);
#pragma unroll
        for (int n = 0; n < 8; ++n) {
            u32 lo, hi;
            asm("v_cvt_pk_bf16_f32 %0, %1, %2"
                : "=v"(lo) : "v"(saA[n][0]), "v"(saA[n][1]));
            asm("v_cvt_pk_bf16_f32 %0, %1, %2"
                : "=v"(hi) : "v"(saA[n][2]), "v"(saA[n][3]));
            u32x2 tmpa = {lo, hi};
            s16x4 pnA = __builtin_bit_cast(s16x4, tmpa);
            asm("v_cvt_pk_bf16_f32 %0, %1, %2"
                : "=v"(lo) : "v"(saB[n][0]), "v"(saB[n][1]));
            asm("v_cvt_pk_bf16_f32 %0, %1, %2"
                : "=v"(hi) : "v"(saB[n][2]), "v"(saB[n][3]));
            u32x2 tmpb = {lo, hi};
            s16x4 pnB = __builtin_bit_cast(s16x4, tmpb);
            laccA = __builtin_amdgcn_mfma_f32_16x16x16bf16_1k(ones, pnA,
                                                              laccA, 0, 0, 0);
            laccB = __builtin_amdgcn_mfma_f32_16x16x16bf16_1k(ones, pnB,
                                                              laccB, 0, 0, 0);
#pragma unroll
            for (int nn = 0; nn < 4; ++nn) {
                s16x4 va = *(const s16x4*)(Vc + (nn * 16 + lr) * 256 +
                                           (((2 * n + (lg >> 1)) ^ (lr & 7)) << 4) +
                                           ((lg & 1) << 3));
                oaccA[nn] = __builtin_amdgcn_mfma_f32_16x16x16bf16_1k(va, pnA,
                                                                      oaccA[nn],
                                                                      0, 0, 0);
                oaccB[nn] = __builtin_amdgcn_mfma_f32_16x16x16bf16_1k(va, pnB,
                                                                      oaccB[nn],
                                                                      0, 0, 0);
            }
        }
        __builtin_amdgcn_s_setprio(0);

        asm volatile("s_waitcnt vmcnt(0)" ::: "memory");
        __builtin_amdgcn_s_barrier();
        __builtin_amdgcn_sched_barrier(0);
    }

    const float linvA = 1.0f / laccA[0];
    const float linvB = 1.0f / laccB[0];
    u16* ow = smem + w * (32 * 72);
#pragma unroll
    for (int nn = 0; nn < 4; ++nn)
#pragma unroll
        for (int r = 0; r < 4; ++r) {
            ow[lr * 72 + nn * 16 + 4 * lg + r] = f2bf(oaccA[nn][r] * linvA);
            ow[(16 + lr) * 72 + nn * 16 + 4 * lg + r] = f2bf(oaccB[nn][r] * linvB);
        }
    __syncthreads();
    const int q_ = lane >> 2, d0 = (lane & 3) << 4;
    const u16* orowA = smem + w * (32 * 72) + q_ * 72 + d0;
    const u16* orowB = orowA + 16 * 72;
    u16x8 a0 = *(const u16x8*)(orowA);
    u16x8 a1 = *(const u16x8*)(orowA + 8);
    u16x8 b0 = *(const u16x8*)(orowB);
    u16x8 b1 = *(const u16x8*)(orowB + 8);
    size_t gaddr = ((size_t)bb * 2048 + q0 + w * 32 + q_) * 1024 + h * 64 + d0;
    *(u16x8*)(ao + gaddr) = a0;
    *(u16x8*)(ao + gaddr + 8) = a1;
    *(u16x8*)(ao + gaddr + 16 * 1024) = b0;
    *(u16x8*)(ao + gaddr + 16 * 1024 + 8) = b1;
}

// ---------------------------------------------------------------- launch
extern "C" void kernel_launch(void* const* d_in, const int* in_sizes, int n_in,
                              void* d_out, int out_size, void* d_ws, size_t ws_size,
                              hipStream_t stream) {
    const float* x  = (const float*)d_in[0];
    const float* Wq = (const float*)d_in[1];
    const float* bq = (const float*)d_in[2];
    const float* Wk = (const float*)d_in[3];
    const float* bk = (const float*)d_in[4];
    const float* Wv = (const float*)d_in[5];
    const float* bv = (const float*)d_in[6];
    const float* Wo = (const float*)d_in[7];
    const float* bo = (const float*)d_in[8];

    const size_t MB = 1u << 20;
    if (ws_size < 40 * MB) return;
    char* ws = (char*)d_ws;
    u16* xb    = (u16*)(ws);             // 8MB  [4096][1024] bf16 (reused as ao)
    u16* wqkvt = (u16*)(ws + 8 * MB);    // 6MB  [3072][1024] = [Wq^T;Wk^T;Wv^T]
    u16* wot   = (u16*)(ws + 14 * MB);   // 2MB  Wo^T
    u16* qb    = (u16*)(ws + 16 * MB);   // 8MB  [32][2048][64]
    u16* kb    = (u16*)(ws + 24 * MB);   // 8MB  [32][2048][64]
    u16* vt    = (u16*)(ws + 32 * MB);   // 8MB  [32][64][2048]
    u16* ao    = xb;

    cvt_all_k<<<dim3(16, 16, 12), 256, 0, stream>>>(Wq, Wk, Wv, Wo, x,
                                                    wqkvt, wot, xb);

    gemm_k<0><<<dim3(32, 24), 256, 0, stream>>>(xb, wqkvt, bq, bk, bv,
                                                qb, kb, vt, nullptr);
    attn_k<<<dim3(16, 32), 256, 0, stream>>>(qb, kb, vt, ao);
    gemm_k<1><<<dim3(32, 8), 256, 0, stream>>>(ao, wot, bo, nullptr, nullptr,
                                               nullptr, nullptr, nullptr,
                                               (float*)d_out);
}

// Round 16
// 107.846 us; speedup vs baseline: 1.2379x; 1.0507x over previous
//
#include <hip/hip_runtime.h>
#include <cstdint>
#include <cstddef>

typedef unsigned short u16;
typedef unsigned int u32;
typedef __bf16 bf16x8 __attribute__((ext_vector_type(8)));
typedef float f32x4 __attribute__((ext_vector_type(4)));
typedef u32 u32x2 __attribute__((ext_vector_type(2)));
typedef u32 u32x4 __attribute__((ext_vector_type(4)));
typedef unsigned short u16x8 __attribute__((ext_vector_type(8)));
typedef short s16x4 __attribute__((ext_vector_type(4)));

// f32 -> bf16 round-to-nearest-even (finite inputs only)
__device__ __forceinline__ u16 f2bf(float f) {
    u32 u = __float_as_uint(f);
    u += 0x7fffu + ((u >> 16) & 1u);
    return (u16)(u >> 16);
}

// raw exp2: single v_exp_f32 (denormals flush to 0 = correct softmax tail)
__device__ __forceinline__ float fexp2(float x) {
    float r;
    asm("v_exp_f32 %0, %1" : "=v"(r) : "v"(x));
    return r;
}

// async global->LDS, 16B per lane. LDS ptr must be wave-uniform; HW adds lane*16.
__device__ __forceinline__ void gl16(const void* g, void* l) {
    __builtin_amdgcn_global_load_lds(
        (const __attribute__((address_space(1))) unsigned int*)g,
        (__attribute__((address_space(3))) unsigned int*)l, 16, 0, 0);
}

// ---------------------------------------------------------------- conversions
// z 0..3: W [1024][1024] f32 (k,n) -> bf16 (n,k). z 4..11: x f32 -> bf16 chunks.
__global__ __launch_bounds__(256) void cvt_all_k(const float* __restrict__ Wq,
                                                 const float* __restrict__ Wk,
                                                 const float* __restrict__ Wv,
                                                 const float* __restrict__ Wo,
                                                 const float* __restrict__ x,
                                                 u16* __restrict__ oqkv,
                                                 u16* __restrict__ oo,
                                                 u16* __restrict__ ox) {
    const int z = blockIdx.z;
    const int bx = blockIdx.x, by = blockIdx.y;
    const int t = threadIdx.x;
    if (z >= 4) {   // x conversion: 8 f32 per thread
        int i = ((z - 4) * 256 + by * 16 + bx) * 256 + t;
        const float4* xv = (const float4*)x;
        float4 a = xv[2 * i], b = xv[2 * i + 1];
        ushort4 r0, r1;
        r0.x = f2bf(a.x); r0.y = f2bf(a.y); r0.z = f2bf(a.z); r0.w = f2bf(a.w);
        r1.x = f2bf(b.x); r1.y = f2bf(b.y); r1.z = f2bf(b.z); r1.w = f2bf(b.w);
        ((ushort4*)ox)[2 * i] = r0;
        ((ushort4*)ox)[2 * i + 1] = r1;
        return;
    }
    __shared__ float tile[64][65];
    const float* W = (z == 0) ? Wq : (z == 1) ? Wk : (z == 2) ? Wv : Wo;
    u16* o = (z < 3) ? (oqkv + ((size_t)z << 20)) : oo;
    const int tn = t & 63, tr = t >> 6;
#pragma unroll
    for (int r = 0; r < 16; ++r) {
        int kk = r * 4 + tr;
        tile[kk][tn] = W[(size_t)(by * 64 + kk) * 1024 + bx * 64 + tn];
    }
    __syncthreads();
#pragma unroll
    for (int r = 0; r < 16; ++r) {
        int nn = r * 4 + tr;
        o[(size_t)(bx * 64 + nn) * 1024 + by * 64 + tn] = f2bf(tile[tn][nn]);
    }
}

// ---------------------------------------------------------------- GEMM 128x128
// 3-buffer depth-2 counted-vmcnt pipeline; zero-conflict both-sides swizzle.
// MODE 0: fused QKV epilogue; V-blocks store via LDS transpose (coalesced).
// MODE 1: f32 out + bias.
template <int MODE>
__global__ __launch_bounds__(256) void gemm_k(
    const u16* __restrict__ A, const u16* __restrict__ Bt,
    const float* __restrict__ bias0, const float* __restrict__ bias1,
    const float* __restrict__ bias2,
    u16* __restrict__ oq, u16* __restrict__ ok_, u16* __restrict__ ov,
    float* __restrict__ oc) {
    __shared__ __align__(16) u16 sh[2 * 3 * 128 * 32];   // 48KB total
    u16* As = sh;
    u16* Bs = sh + 3 * 128 * 32;
    const int t = threadIdx.x, w = t >> 6, lane = t & 63;
    const int lr = lane & 15, lg = lane >> 4;
    const int brow = blockIdx.x * 128, bcol = blockIdx.y * 128;
    const int wr = w >> 1, wc = w & 1;
    const char* Ab = (const char*)A + (size_t)brow * 2048;
    const char* Bb = (const char*)Bt + (size_t)bcol * 2048;
    const int lrow = lane >> 2;
    const int lcol = (((lane & 3) ^ ((lane >> 3) & 3)) << 4);
    const int r0a = w * 32, r0b = w * 32 + 16;
    const size_t ga = (size_t)(r0a + lrow) * 2048 + lcol;
    const size_t gb = (size_t)(r0b + lrow) * 2048 + lcol;
    const int rsw = ((lg ^ ((lr >> 1) & 3)) << 4);

    f32x4 acc[4][4];
#pragma unroll
    for (int m = 0; m < 4; ++m)
#pragma unroll
        for (int n = 0; n < 4; ++n) acc[m][n] = (f32x4){0.f, 0.f, 0.f, 0.f};

    gl16(Ab + ga, (char*)As + r0a * 64);
    gl16(Ab + gb, (char*)As + r0b * 64);
    gl16(Bb + ga, (char*)Bs + r0a * 64);
    gl16(Bb + gb, (char*)Bs + r0b * 64);
    gl16(Ab + ga + 64, (char*)As + 8192 + r0a * 64);
    gl16(Ab + gb + 64, (char*)As + 8192 + r0b * 64);
    gl16(Bb + ga + 64, (char*)Bs + 8192 + r0a * 64);
    gl16(Bb + gb + 64, (char*)Bs + 8192 + r0b * 64);

    for (int tt = 0; tt < 32; ++tt) {
        if (tt < 31) {
            asm volatile("s_waitcnt vmcnt(4)" ::: "memory");
        } else {
            asm volatile("s_waitcnt vmcnt(0)" ::: "memory");
        }
        __builtin_amdgcn_s_barrier();
        __builtin_amdgcn_sched_barrier(0);
        if (tt < 30) {
            const int nb = (tt + 2) % 3;
            const size_t ko = (size_t)(tt + 2) * 64;
            char* Asn = (char*)As + nb * 8192;
            char* Bsn = (char*)Bs + nb * 8192;
            gl16(Ab + ga + ko, Asn + r0a * 64);
            gl16(Ab + gb + ko, Asn + r0b * 64);
            gl16(Bb + ga + ko, Bsn + r0a * 64);
            gl16(Bb + gb + ko, Bsn + r0b * 64);
        }
        const char* AsB = (const char*)As + (tt % 3) * 8192;
        const char* BsB = (const char*)Bs + (tt % 3) * 8192;
        bf16x8 af[4], bfr[4];
#pragma unroll
        for (int m = 0; m < 4; ++m)
            af[m] = *(const bf16x8*)(AsB + (wr * 64 + m * 16 + lr) * 64 + rsw);
#pragma unroll
        for (int n = 0; n < 4; ++n)
            bfr[n] = *(const bf16x8*)(BsB + (wc * 64 + n * 16 + lr) * 64 + rsw);
#pragma unroll
        for (int m = 0; m < 4; ++m)
#pragma unroll
            for (int n = 0; n < 4; ++n)
                acc[m][n] = __builtin_amdgcn_mfma_f32_16x16x32_bf16(af[m], bfr[n],
                                                                    acc[m][n], 0, 0, 0);
    }

    const float QSCALE = 0.125f * 1.44269504f;
    if (MODE == 0 && bcol >= 2048) {
        // V block: transpose via LDS, store coalesced 128B runs into vt.
        const int b = brow >> 11, l0 = brow & 2047;
        __syncthreads();
#pragma unroll
        for (int n = 0; n < 4; ++n) {
            const int cl = wc * 64 + n * 16 + lr;
            const float bb2 = bias2[bcol - 2048 + cl];
#pragma unroll
            for (int m = 0; m < 4; ++m)
#pragma unroll
                for (int r = 0; r < 4; ++r) {
                    int ll = wr * 64 + m * 16 + 4 * lg + r;
                    sh[cl * 136 + ll] = f2bf(acc[m][n][r] + bb2);
                }
        }
        __syncthreads();
        const int rr = t >> 1, hf = t & 1;
        const u16* src = sh + rr * 136 + hf * 64;
        u16* dst = ov + ((size_t)b * 1024 + (bcol - 2048) + rr) * 2048 +
                   l0 + hf * 64;
#pragma unroll
        for (int i = 0; i < 8; ++i)
            *(u16x8*)(dst + i * 8) = *(const u16x8*)(src + i * 8);
        return;
    }
#pragma unroll
    for (int n = 0; n < 4; ++n) {
        const int col = bcol + wc * 64 + n * 16 + lr;
        if (MODE == 0) {
#pragma unroll
            for (int m = 0; m < 4; ++m)
#pragma unroll
                for (int r = 0; r < 4; ++r) {
                    int row = brow + wr * 64 + m * 16 + 4 * lg + r;
                    int b = row >> 11, l = row & 2047;
                    float val = acc[m][n][r];
                    if (col < 1024) {
                        int hh = col >> 6, d = col & 63;
                        oq[(((size_t)b * 16 + hh) * 2048 + l) * 64 + d] =
                            f2bf((val + bias0[col]) * QSCALE);
                    } else {
                        int c = col - 1024, hh = c >> 6, d = c & 63;
                        ok_[(((size_t)b * 16 + hh) * 2048 + l) * 64 + d] =
                            f2bf(val + bias1[c]);
                    }
                }
        } else {
            const float bb = bias0[col];
#pragma unroll
            for (int m = 0; m < 4; ++m)
#pragma unroll
                for (int r = 0; r < 4; ++r) {
                    int row = brow + wr * 64 + m * 16 + 4 * lg + r;
                    oc[(size_t)row * 1024 + col] = acc[m][n][r] + bb;
                }
        }
    }
}

// ---------------------------------------------------------------- attention
// KVBLK=128, 2-buffer depth-1, 32-row waves, max-free softmax in MFMA C-init.
// PV via K=32 MFMA with CONCATENATED slice pairs: B-frag = concat(pn[2np],
// pn[2np+1]) (k=8lg+e, e<4 -> slice 2np j=4lg+e, e>=4 -> slice 2np+1), A-frag
// = concat(va[2np], va[2np+1]) (same k map; va's swizzled addr = linear
// 32n+8lg). No exchange. PV 64 K=16 -> 32 K=32; l 16 K=16 -> 8 K=32.
__global__ __launch_bounds__(256, 2) void attn_k(const u16* __restrict__ qg_,
                                                 const u16* __restrict__ kg_,
                                                 const u16* __restrict__ vg_,
                                                 u16* __restrict__ ao) {
    __shared__ __align__(16) u16 smem[32768];   // 64KB: K0|K1 | V0|V1 (16KB ea)
    char* Kbase = (char*)smem;                  // 2 x 16384
    char* Vbase = (char*)smem + 32768;          // 2 x 16384
    const int t = threadIdx.x, w = t >> 6, lane = t & 63;
    const int lr = lane & 15, lg = lane >> 4;
    const int bid = blockIdx.y * 16 + blockIdx.x;
    const int qt = (bid >> 3) & 15;
    const int bh = ((bid >> 7) << 3) | (bid & 7);
    const int q0 = qt * 128, h = bh & 15, bb = bh >> 4;
    const float sl2 = exp2f(-0.5f * (float)(h + 1)) * 1.44269504f; // slope*log2e

    const char* khead = (const char*)(kg_ + (size_t)bh * 2048 * 64);
    const char* vhead = (const char*)(vg_ + (size_t)bh * 64 * 2048);

    const int krow = lane >> 3, ku = lane & 7;
    const int kso = (w * 32 + krow) * 128 + ((ku ^ (krow & 7)) << 4);
    const int kdo = w * 4096;
    const int vrow = lane >> 4, vgr = lane & 15;
    int vso[4];
#pragma unroll
    for (int i = 0; i < 4; ++i)
        vso[i] = (w * 16 + 4 * i + vrow) * 4096 +
                 ((vgr ^ ((4 * i + vrow) & 7)) << 4);
    const int vdo = w * 4096;

    const char* qpA = (const char*)qg_ +
                      ((size_t)bh * 2048 + q0 + w * 32 + lr) * 128;
    bf16x8 qa0A = *(const bf16x8*)(qpA + lg * 16);
    bf16x8 qa1A = *(const bf16x8*)(qpA + 64 + lg * 16);
    bf16x8 qa0B = *(const bf16x8*)(qpA + 2048 + lg * 16);
    bf16x8 qa1B = *(const bf16x8*)(qpA + 2048 + 64 + lg * 16);

    f32x4 abF2[8];
#pragma unroll
    for (int n = 0; n < 8; ++n)
#pragma unroll
        for (int r = 0; r < 4; ++r)
            abF2[n][r] = sl2 * (float)(n * 16 + 4 * lg + r - 2047) - 16.0f;
    const float ainc = sl2 * 128.0f;
    f32x4 oaccA[4], oaccB[4];
#pragma unroll
    for (int nn = 0; nn < 4; ++nn) {
        oaccA[nn] = (f32x4){0.f, 0.f, 0.f, 0.f};
        oaccB[nn] = (f32x4){0.f, 0.f, 0.f, 0.f};
    }
    f32x4 laccA = (f32x4){0.f, 0.f, 0.f, 0.f};
    f32x4 laccB = (f32x4){0.f, 0.f, 0.f, 0.f};
    const u32x4 ones32 = {0x3F803F80u, 0x3F803F80u, 0x3F803F80u, 0x3F803F80u};
    const bf16x8 onesf = __builtin_bit_cast(bf16x8, ones32);

    {
        char* kd = Kbase + kdo;
        char* vd = Vbase + vdo;
#pragma unroll
        for (int i = 0; i < 4; ++i) gl16(khead + kso + i * 1024, kd + i * 1024);
#pragma unroll
        for (int i = 0; i < 4; ++i) gl16(vhead + vso[i], vd + i * 1024);
    }
    asm volatile("s_waitcnt vmcnt(0)" ::: "memory");
    __builtin_amdgcn_s_barrier();
    __builtin_amdgcn_sched_barrier(0);

    for (int tt = 0; tt < 16; ++tt) {
        if (tt < 15) {
            const char* ks = khead + (size_t)(tt + 1) * 16384;
            const char* vs = vhead + (size_t)(tt + 1) * 256;
            char* kd = Kbase + ((tt + 1) & 1) * 16384 + kdo;
            char* vd = Vbase + ((tt + 1) & 1) * 16384 + vdo;
#pragma unroll
            for (int i = 0; i < 4; ++i) gl16(ks + kso + i * 1024, kd + i * 1024);
#pragma unroll
            for (int i = 0; i < 4; ++i) gl16(vs + vso[i], vd + i * 1024);
        }
        const char* Kc = Kbase + (tt & 1) * 16384;
        const char* Vc = Vbase + (tt & 1) * 16384;

        f32x4 saA[8], saB[8];
        __builtin_amdgcn_s_setprio(1);
#pragma unroll
        for (int n = 0; n < 8; ++n) {
            bf16x8 kf = *(const bf16x8*)(Kc + (n * 16 + lr) * 128 +
                                         ((lg ^ (lr & 7)) << 4));
            saA[n] = __builtin_amdgcn_mfma_f32_16x16x32_bf16(kf, qa0A, abF2[n],
                                                             0, 0, 0);
            saB[n] = __builtin_amdgcn_mfma_f32_16x16x32_bf16(kf, qa0B, abF2[n],
                                                             0, 0, 0);
        }
#pragma unroll
        for (int n = 0; n < 8; ++n) {
            bf16x8 kf = *(const bf16x8*)(Kc + (n * 16 + lr) * 128 +
                                         (((4 + lg) ^ (lr & 7)) << 4));
            saA[n] = __builtin_amdgcn_mfma_f32_16x16x32_bf16(kf, qa1A, saA[n],
                                                             0, 0, 0);
            saB[n] = __builtin_amdgcn_mfma_f32_16x16x32_bf16(kf, qa1B, saB[n],
                                                             0, 0, 0);
        }
        __builtin_amdgcn_s_setprio(0);

        // max-free softmax: P = exp2(sa)
#pragma unroll
        for (int n = 0; n < 8; ++n)
#pragma unroll
            for (int r = 0; r < 4; ++r) {
                saA[n][r] = fexp2(saA[n][r]);
                saB[n][r] = fexp2(saB[n][r]);
            }
#pragma unroll
        for (int n = 0; n < 8; ++n) abF2[n] += ainc;

        // pack all 8 slices to bf16 pairs (pX[n] = {j=4lg+0..1, j=4lg+2..3})
        u32 pA[8][2], pB[8][2];
#pragma unroll
        for (int n = 0; n < 8; ++n) {
            asm("v_cvt_pk_bf16_f32 %0, %1, %2"
                : "=v"(pA[n][0]) : "v"(saA[n][0]), "v"(saA[n][1]));
            asm("v_cvt_pk_bf16_f32 %0, %1, %2"
                : "=v"(pA[n][1]) : "v"(saA[n][2]), "v"(saA[n][3]));
            asm("v_cvt_pk_bf16_f32 %0, %1, %2"
                : "=v"(pB[n][0]) : "v"(saB[n][0]), "v"(saB[n][1]));
            asm("v_cvt_pk_bf16_f32 %0, %1, %2"
                : "=v"(pB[n][1]) : "v"(saB[n][2]), "v"(saB[n][3]));
        }

        // PV + l per 32-j slice-pair: K=32 MFMA, concatenated frags
        __builtin_amdgcn_s_setprio(1);
#pragma unroll
        for (int np = 0; np < 4; ++np) {
            const int n0 = 2 * np, n1 = 2 * np + 1;
            u32x4 bwA = {pA[n0][0], pA[n0][1], pA[n1][0], pA[n1][1]};
            u32x4 bwB = {pB[n0][0], pB[n0][1], pB[n1][0], pB[n1][1]};
            bf16x8 pfA = __builtin_bit_cast(bf16x8, bwA);
            bf16x8 pfB = __builtin_bit_cast(bf16x8, bwB);
            laccA = __builtin_amdgcn_mfma_f32_16x16x32_bf16(onesf, pfA,
                                                            laccA, 0, 0, 0);
            laccB = __builtin_amdgcn_mfma_f32_16x16x32_bf16(onesf, pfB,
                                                            laccB, 0, 0, 0);
#pragma unroll
            for (int nn = 0; nn < 4; ++nn) {
                s16x4 v0 = *(const s16x4*)(Vc + (nn * 16 + lr) * 256 +
                                           (((2 * n0 + (lg >> 1)) ^ (lr & 7)) << 4) +
                                           ((lg & 1) << 3));
                s16x4 v1 = *(const s16x4*)(Vc + (nn * 16 + lr) * 256 +
                                           (((2 * n1 + (lg >> 1)) ^ (lr & 7)) << 4) +
                                           ((lg & 1) << 3));
                u32x2 w0 = __builtin_bit_cast(u32x2, v0);
                u32x2 w1 = __builtin_bit_cast(u32x2, v1);
                u32x4 aw = {w0[0], w0[1], w1[0], w1[1]};
                bf16x8 vaf = __builtin_bit_cast(bf16x8, aw);
                oaccA[nn] = __builtin_amdgcn_mfma_f32_16x16x32_bf16(vaf, pfA,
                                                                    oaccA[nn],
                                                                    0, 0, 0);
                oaccB[nn] = __builtin_amdgcn_mfma_f32_16x16x32_bf16(vaf, pfB,
                                                                    oaccB[nn],
                                                                    0, 0, 0);
            }
        }
        __builtin_amdgcn_s_setprio(0);

        asm volatile("s_waitcnt vmcnt(0)" ::: "memory");
        __builtin_amdgcn_s_barrier();
        __builtin_amdgcn_sched_barrier(0);
    }

    const float linvA = 1.0f / laccA[0];
    const float linvB = 1.0f / laccB[0];
    u16* ow = smem + w * (32 * 72);
#pragma unroll
    for (int nn = 0; nn < 4; ++nn)
#pragma unroll
        for (int r = 0; r < 4; ++r) {
            ow[lr * 72 + nn * 16 + 4 * lg + r] = f2bf(oaccA[nn][r] * linvA);
            ow[(16 + lr) * 72 + nn * 16 + 4 * lg + r] = f2bf(oaccB[nn][r] * linvB);
        }
    __syncthreads();
    const int q_ = lane >> 2, d0 = (lane & 3) << 4;
    const u16* orowA = smem + w * (32 * 72) + q_ * 72 + d0;
    const u16* orowB = orowA + 16 * 72;
    u16x8 a0 = *(const u16x8*)(orowA);
    u16x8 a1 = *(const u16x8*)(orowA + 8);
    u16x8 b0 = *(const u16x8*)(orowB);
    u16x8 b1 = *(const u16x8*)(orowB + 8);
    size_t gaddr = ((size_t)bb * 2048 + q0 + w * 32 + q_) * 1024 + h * 64 + d0;
    *(u16x8*)(ao + gaddr) = a0;
    *(u16x8*)(ao + gaddr + 8) = a1;
    *(u16x8*)(ao + gaddr + 16 * 1024) = b0;
    *(u16x8*)(ao + gaddr + 16 * 1024 + 8) = b1;
}

// ---------------------------------------------------------------- launch
extern "C" void kernel_launch(void* const* d_in, const int* in_sizes, int n_in,
                              void* d_out, int out_size, void* d_ws, size_t ws_size,
                              hipStream_t stream) {
    const float* x  = (const float*)d_in[0];
    const float* Wq = (const float*)d_in[1];
    const float* bq = (const float*)d_in[2];
    const float* Wk = (const float*)d_in[3];
    const float* bk = (const float*)d_in[4];
    const float* Wv = (const float*)d_in[5];
    const float* bv = (const float*)d_in[6];
    const float* Wo = (const float*)d_in[7];
    const float* bo = (const float*)d_in[8];

    const size_t MB = 1u << 20;
    if (ws_size < 40 * MB) return;
    char* ws = (char*)d_ws;
    u16* xb    = (u16*)(ws);             // 8MB  [4096][1024] bf16 (reused as ao)
    u16* wqkvt = (u16*)(ws + 8 * MB);    // 6MB  [3072][1024] = [Wq^T;Wk^T;Wv^T]
    u16* wot   = (u16*)(ws + 14 * MB);   // 2MB  Wo^T
    u16* qb    = (u16*)(ws + 16 * MB);   // 8MB  [32][2048][64]
    u16* kb    = (u16*)(ws + 24 * MB);   // 8MB  [32][2048][64]
    u16* vt    = (u16*)(ws + 32 * MB);   // 8MB  [32][64][2048]
    u16* ao    = xb;

    cvt_all_k<<<dim3(16, 16, 12), 256, 0, stream>>>(Wq, Wk, Wv, Wo, x,
                                                    wqkvt, wot, xb);

    gemm_k<0><<<dim3(32, 24), 256, 0, stream>>>(xb, wqkvt, bq, bk, bv,
                                                qb, kb, vt, nullptr);
    attn_k<<<dim3(16, 32), 256, 0, stream>>>(qb, kb, vt, ao);
    gemm_k<1><<<dim3(32, 8), 256, 0, stream>>>(ao, wot, bo, nullptr, nullptr,
                                               nullptr, nullptr, nullptr,
                                               (float*)d_out);
}